// Round 17
// baseline (83.103 us; speedup 1.0000x reference)
//
#include <hip/hip_runtime.h>
#include <math.h>

#define EPSF 1e-8f

typedef float f2v __attribute__((ext_vector_type(2)));

__device__ __forceinline__ float bcf(int x){ return __builtin_bit_cast(float, x); }
__device__ __forceinline__ int   bci(float x){ return __builtin_bit_cast(int, x); }

template<int CTRL, int RM>
__device__ __forceinline__ float dpp0(float v){
  return bcf(__builtin_amdgcn_update_dpp(0, bci(v), CTRL, RM, 0xF, false));
}
__device__ __forceinline__ float rl(float v, int l){
  return bcf(__builtin_amdgcn_readlane(bci(v), l));
}
__device__ __forceinline__ float wave_iscan_add(float v){
  v += dpp0<0x111,0xF>(v);
  v += dpp0<0x112,0xF>(v);
  v += dpp0<0x114,0xF>(v);
  v += dpp0<0x118,0xF>(v);
  v += dpp0<0x142,0xA>(v);
  v += dpp0<0x143,0xC>(v);
  return v;
}
__device__ __forceinline__ float wave_red_add(float v){ return wave_iscan_add(v); } // lane63 = total
__device__ __forceinline__ float wave_red_max_pos(float v){ // v >= 0
  v = fmaxf(v, dpp0<0x111,0xF>(v));
  v = fmaxf(v, dpp0<0x112,0xF>(v));
  v = fmaxf(v, dpp0<0x114,0xF>(v));
  v = fmaxf(v, dpp0<0x118,0xF>(v));
  v = fmaxf(v, dpp0<0x142,0xA>(v));
  v = fmaxf(v, dpp0<0x143,0xC>(v));
  return v;
}

// 16B-unit swizzle: slot(low3) ^= i[5:3]. Verified at the b128 floor (R13).
__device__ __forceinline__ int FL8(int i){ return i ^ ((i >> 3) & 7); }

// In-place 8-point complex DFT, packed over 2 rows (f2v = {rowA, rowB}).
__device__ __forceinline__ void dft8p(f2v* ar, f2v* ai){
  const float C = 0.70710678118654752f;
  const f2v t0r=ar[0]+ar[4], t0i=ai[0]+ai[4];
  const f2v t1r=ar[0]-ar[4], t1i=ai[0]-ai[4];
  const f2v t2r=ar[2]+ar[6], t2i=ai[2]+ai[6];
  const f2v t3r=ar[2]-ar[6], t3i=ai[2]-ai[6];
  const f2v E0r=t0r+t2r, E0i=t0i+t2i;
  const f2v E1r=t1r+t3i, E1i=t1i-t3r;
  const f2v E2r=t0r-t2r, E2i=t0i-t2i;
  const f2v E3r=t1r-t3i, E3i=t1i+t3r;
  const f2v u0r=ar[1]+ar[5], u0i=ai[1]+ai[5];
  const f2v u1r=ar[1]-ar[5], u1i=ai[1]-ai[5];
  const f2v u2r=ar[3]+ar[7], u2i=ai[3]+ai[7];
  const f2v u3r=ar[3]-ar[7], u3i=ai[3]-ai[7];
  const f2v O0r=u0r+u2r, O0i=u0i+u2i;
  const f2v O1r=u1r+u3i, O1i=u1i-u3r;
  const f2v O2r=u0r-u2r, O2i=u0i-u2i;
  const f2v O3r=u1r-u3i, O3i=u1i+u3r;
  const f2v w1r =  C*(O1r+O1i), w1i = C*(O1i-O1r);
  const f2v w2r =  O2i,         w2i = -O2r;
  const f2v w3r =  C*(O3i-O3r), w3i = -C*(O3r+O3i);
  ar[0]=E0r+O0r; ai[0]=E0i+O0i;
  ar[4]=E0r-O0r; ai[4]=E0i-O0i;
  ar[1]=E1r+w1r; ai[1]=E1i+w1i;
  ar[5]=E1r-w1r; ai[5]=E1i-w1i;
  ar[2]=E2r+w2r; ai[2]=E2i+w2i;
  ar[6]=E2r-w2r; ai[6]=E2i-w2i;
  ar[3]=E3r+w3r; ai[3]=E3i+w3i;
  ar[7]=E3r-w3r; ai[7]=E3i-w3i;
}

// stats LDS slots (per wave, per row): 0 SUMSQ, 1 ALT, 2..11 R1..R10, 12 STR,
// 13 STR2, 14 SC, 15 SC2, 16 SUMX, 17..26 Slo, 27..36 Shi pool, 37 x0, 38 xl
__global__ void __launch_bounds__(128, 2)
sr_kernel(const float* __restrict__ x,
          const float* __restrict__ ln_w, const float* __restrict__ ln_b,
          const float* __restrict__ w1, const float* __restrict__ b1,
          const float* __restrict__ w2, const float* __restrict__ b2,
          float* __restrict__ out, int B)
{
  // packed complex buffer: unit u holds [Are, Bre, Aim, Bim] (16B)
  __shared__ __align__(16) float bufr2[2][2048];    // 8KB per wave
  __shared__ __align__(16) float stats2[2][2][40];

  const int tid = threadIdx.x;
  const int t   = tid & 63;
  const int wv  = tid >> 6;
  const int rowbase = blockIdx.x * 4 + wv * 2;
  if (rowbase >= B) return;
  float* buff = bufr2[wv];
  float* stA  = stats2[wv][0];
  float* stB  = stats2[wv][1];

  const float* __restrict__ xrA = x + (size_t)rowbase * 1024;
  const float* __restrict__ xrB = xrA + 1024;
  const int c0 = t * 16;

  // ======== ALL global loads for BOTH rows issued up front ========
  float vvA[28], vvB[28], pvA[12], pvB[12];
  {
    const float4 a0 = *reinterpret_cast<const float4*>(xrA + c0);
    const float4 a1 = *reinterpret_cast<const float4*>(xrA + c0 + 4);
    const float4 a2 = *reinterpret_cast<const float4*>(xrA + c0 + 8);
    const float4 a3 = *reinterpret_cast<const float4*>(xrA + c0 + 12);
    vvA[0]=a0.x; vvA[1]=a0.y; vvA[2]=a0.z; vvA[3]=a0.w;
    vvA[4]=a1.x; vvA[5]=a1.y; vvA[6]=a1.z; vvA[7]=a1.w;
    vvA[8]=a2.x; vvA[9]=a2.y; vvA[10]=a2.z; vvA[11]=a2.w;
    vvA[12]=a3.x; vvA[13]=a3.y; vvA[14]=a3.z; vvA[15]=a3.w;
    const float4 b0 = *reinterpret_cast<const float4*>(xrB + c0);
    const float4 b1_ = *reinterpret_cast<const float4*>(xrB + c0 + 4);
    const float4 b2_ = *reinterpret_cast<const float4*>(xrB + c0 + 8);
    const float4 b3 = *reinterpret_cast<const float4*>(xrB + c0 + 12);
    vvB[0]=b0.x; vvB[1]=b0.y; vvB[2]=b0.z; vvB[3]=b0.w;
    vvB[4]=b1_.x; vvB[5]=b1_.y; vvB[6]=b1_.z; vvB[7]=b1_.w;
    vvB[8]=b2_.x; vvB[9]=b2_.y; vvB[10]=b2_.z; vvB[11]=b2_.w;
    vvB[12]=b3.x; vvB[13]=b3.y; vvB[14]=b3.z; vvB[15]=b3.w;
  }
  if (t < 63) {
    const float4 n0 = *reinterpret_cast<const float4*>(xrA + c0 + 16);
    const float4 n1 = *reinterpret_cast<const float4*>(xrA + c0 + 20);
    const float4 n2 = *reinterpret_cast<const float4*>(xrA + c0 + 24);
    vvA[16]=n0.x; vvA[17]=n0.y; vvA[18]=n0.z; vvA[19]=n0.w;
    vvA[20]=n1.x; vvA[21]=n1.y; vvA[22]=n1.z; vvA[23]=n1.w;
    vvA[24]=n2.x; vvA[25]=n2.y; vvA[26]=n2.z; vvA[27]=n2.w;
    const float4 m0 = *reinterpret_cast<const float4*>(xrB + c0 + 16);
    const float4 m1 = *reinterpret_cast<const float4*>(xrB + c0 + 20);
    const float4 m2 = *reinterpret_cast<const float4*>(xrB + c0 + 24);
    vvB[16]=m0.x; vvB[17]=m0.y; vvB[18]=m0.z; vvB[19]=m0.w;
    vvB[20]=m1.x; vvB[21]=m1.y; vvB[22]=m1.z; vvB[23]=m1.w;
    vvB[24]=m2.x; vvB[25]=m2.y; vvB[26]=m2.z; vvB[27]=m2.w;
  } else {
#pragma unroll
    for (int j = 16; j < 28; ++j) { vvA[j] = 0.f; vvB[j] = 0.f; }
  }
  if (t > 0) {
    const float4 p0 = *reinterpret_cast<const float4*>(xrA + c0 - 12);
    const float4 p1 = *reinterpret_cast<const float4*>(xrA + c0 - 8);
    const float4 p2 = *reinterpret_cast<const float4*>(xrA + c0 - 4);
    pvA[0]=p0.x; pvA[1]=p0.y; pvA[2]=p0.z; pvA[3]=p0.w;
    pvA[4]=p1.x; pvA[5]=p1.y; pvA[6]=p1.z; pvA[7]=p1.w;
    pvA[8]=p2.x; pvA[9]=p2.y; pvA[10]=p2.z; pvA[11]=p2.w;
    const float4 q0 = *reinterpret_cast<const float4*>(xrB + c0 - 12);
    const float4 q1 = *reinterpret_cast<const float4*>(xrB + c0 - 8);
    const float4 q2 = *reinterpret_cast<const float4*>(xrB + c0 - 4);
    pvB[0]=q0.x; pvB[1]=q0.y; pvB[2]=q0.z; pvB[3]=q0.w;
    pvB[4]=q1.x; pvB[5]=q1.y; pvB[6]=q1.z; pvB[7]=q1.w;
    pvB[8]=q2.x; pvB[9]=q2.y; pvB[10]=q2.z; pvB[11]=q2.w;
  } else {
#pragma unroll
    for (int j = 0; j < 12; ++j) { pvA[j] = 0.f; pvB[j] = 0.f; }
  }

  // ---- stash both rows into packed layout ----
#pragma unroll
  for (int j = 0; j < 8; ++j) {
    const int fo = FL8(8*t + j) * 4;
    buff[fo]     = vvA[2*j];
    buff[fo + 2] = vvA[2*j + 1];
    buff[fo + 1] = vvB[2*j];
    buff[fo + 3] = vvB[2*j + 1];
  }

  // ======== interleaved stats: two independent scalar chains (A ∥ B) ========
  {
    float sqA = 0.f, sqB = 0.f, alA = 0.f, alB = 0.f;
#pragma unroll
    for (int j = 0; j < 16; ++j) {
      sqA = fmaf(vvA[j], vvA[j], sqA);
      sqB = fmaf(vvB[j], vvB[j], sqB);
      alA += (j & 1) ? -vvA[j] : vvA[j];
      alB += (j & 1) ? -vvB[j] : vvB[j];
    }
    const float rA = wave_red_add(sqA);
    const float rB = wave_red_add(sqB);
    const float aA = wave_red_add(alA);
    const float aB = wave_red_add(alB);
    if (t == 63) { stA[0] = rA; stB[0] = rB; stA[1] = aA; stB[1] = aB; }
  }
#pragma unroll
  for (int k = 1; k <= 10; ++k) {
    float accA = 0.f, accB = 0.f;
#pragma unroll
    for (int j = 0; j < 16; ++j) {
      accA = fmaf(vvA[j], vvA[j+k], accA);
      accB = fmaf(vvB[j], vvB[j+k], accB);
    }
    const float rA = wave_red_add(accA);
    const float rB = wave_red_add(accB);
    if (t == 63) { stA[1 + k] = rA; stB[1 + k] = rB; }
  }

  // ---- prefix scans (no s[] arrays; recompute where needed) ----
  float csA = 0.f, csB = 0.f;
#pragma unroll
  for (int j = 0; j < 16; ++j) { csA += vvA[j]; csB += vvB[j]; }
  const float inclA = wave_iscan_add(csA);
  const float inclB = wave_iscan_add(csB);
  const float exclA = inclA - csA;
  const float exclB = inclB - csB;
  if (t == 63) { stA[16] = inclA; stB[16] = inclB; }
  if (t == 0) {
    float pA = 0.f, pB = 0.f;
#pragma unroll
    for (int q = 0; q < 10; ++q) {
      pA += vvA[q]; pB += vvB[q];
      stA[17 + q] = pA; stB[17 + q] = pB;
    }
    stA[37] = vvA[0]; stB[37] = vvB[0];
  }
  if (t == 63) {
    float pA = exclA, pB = exclB;
#pragma unroll
    for (int j = 0; j < 15; ++j) {
      pA += vvA[j]; pB += vvB[j];
      if (j >= 5) { stA[27 + j - 5] = pA; stB[27 + j - 5] = pB; }
    }
    stA[38] = vvA[15]; stB[38] = vvB[15];
  }

  // ---- trend (sliding +-12 window), A ∥ B ----
  float trvA[16], trvB[16];
  float strA = 0.f, strB = 0.f, sqtA = 0.f, sqtB = 0.f;
  {
    float wsA = 0.f, wsB = 0.f;
#pragma unroll
    for (int j = 0; j < 12; ++j) { wsA += pvA[j]; wsB += pvB[j]; }
#pragma unroll
    for (int j = 0; j <= 12; ++j) { wsA += vvA[j]; wsB += vvB[j]; }
#pragma unroll
    for (int jj = 0; jj < 16; ++jj) {
      if (jj > 0) {
        wsA += vvA[jj + 12] - ((jj < 13) ? pvA[jj - 1] : vvA[jj - 13]);
        wsB += vvB[jj + 12] - ((jj < 13) ? pvB[jj - 1] : vvB[jj - 13]);
      }
      float swA = wsA, swB = wsB;
      if (t == 0  && jj < 12) { swA += (float)(12 - jj) * vvA[0]; swB += (float)(12 - jj) * vvB[0]; }
      if (t == 63 && jj >= 4) { swA += (float)(jj - 3) * vvA[15]; swB += (float)(jj - 3) * vvB[15]; }
      const float tA = swA * 0.04f;
      const float tB = swB * 0.04f;
      trvA[jj] = tA; trvB[jj] = tB;
      strA += tA; strB += tB;
      sqtA = fmaf(tA, tA, sqtA);
      sqtB = fmaf(tB, tB, sqtB);
    }
  }
  const float tinclA = wave_iscan_add(strA);
  const float tinclB = wave_iscan_add(strB);
  {
    const float r2A = wave_red_add(sqtA);
    const float r2B = wave_red_add(sqtB);
    if (t == 63) { stA[12] = tinclA; stB[12] = tinclB; stA[13] = r2A; stB[13] = r2B; }
  }
  // ---- cumsum(resid) stats, prefix regenerated on the fly ----
  {
    float runA = tinclA - strA, runB = tinclB - strB;
    float prA = exclA, prB = exclB;
    float scA = 0.f, scB = 0.f, s2A = 0.f, s2B = 0.f;
#pragma unroll
    for (int jj = 0; jj < 16; ++jj) {
      prA += vvA[jj]; prB += vvB[jj];
      runA += trvA[jj]; runB += trvB[jj];
      const float cA = prA - runA;
      const float cB = prB - runB;
      scA += cA; scB += cB;
      s2A = fmaf(cA, cA, s2A);
      s2B = fmaf(cB, cB, s2B);
    }
    const float rA = wave_red_add(scA);
    const float rB = wave_red_add(scB);
    const float qA = wave_red_add(s2A);
    const float qB = wave_red_add(s2B);
    if (t == 63) { stA[14] = rA; stB[14] = rB; stA[15] = qA; stB[15] = qB; }
  }

  // ==================== packed half-length real FFT (2 rows per wave) ====================
  f2v zr[8], zi[8];
#pragma unroll
  for (int p = 0; p < 8; ++p) {
    const float4 q4 = *reinterpret_cast<const float4*>(&buff[FL8(t + 64*p) * 4]);
    zr[p] = f2v{q4.x, q4.y};
    zi[p] = f2v{q4.z, q4.w};
  }
  dft8p(zr, zi);
  {
    const float a1 = -0.012271846303085130f * (float)t;   // -2pi/512 * t
    const float c1 = __cosf(a1), s1 = __sinf(a1);
    const float c2=c1*c1-s1*s1, s2=2.f*c1*s1;
    const float c3=c2*c1-s2*s1, s3=s2*c1+c2*s1;
    const float c4=c2*c2-s2*s2, s4=2.f*c2*s2;
    const float c5=c4*c1-s4*s1, s5=s4*c1+c4*s1;
    const float c6=c3*c3-s3*s3, s6=2.f*c3*s3;
    const float c7=c6*c1-s6*s1, s7=s6*c1+c6*s1;
    const float cq[8] = {1.f,c1,c2,c3,c4,c5,c6,c7};
    const float sq[8] = {0.f,s1,s2,s3,s4,s5,s6,s7};
#pragma unroll
    for (int q = 1; q < 8; ++q) {
      const f2v r0 = zr[q]*cq[q] - zi[q]*sq[q];
      zi[q] = zr[q]*sq[q] + zi[q]*cq[q];
      zr[q] = r0;
    }
  }
  // transpose 1: unit q*64 + t
#pragma unroll
  for (int q = 0; q < 8; ++q) {
    const int fo = FL8(q*64 + t) * 4;
    *reinterpret_cast<f2v*>(&buff[fo])     = zr[q];
    *reinterpret_cast<f2v*>(&buff[fo + 2]) = zi[q];
  }
  const int qq = t >> 3;
  const int dd = t & 7;
  const int qb = qq << 6;
#pragma unroll
  for (int e = 0; e < 8; ++e) {
    const float4 q4 = *reinterpret_cast<const float4*>(&buff[FL8(qb + dd + 8*e) * 4]);
    zr[e] = f2v{q4.x, q4.y};
    zi[e] = f2v{q4.z, q4.w};
  }
  dft8p(zr, zi);
  {
    const float a1 = -0.098174770424681039f * (float)dd;  // -2pi/64 * d
    const float c1 = __cosf(a1), s1 = __sinf(a1);
    const float c2=c1*c1-s1*s1, s2=2.f*c1*s1;
    const float c3=c2*c1-s2*s1, s3=s2*c1+c2*s1;
    const float c4=c2*c2-s2*s2, s4=2.f*c2*s2;
    const float c5=c4*c1-s4*s1, s5=s4*c1+c4*s1;
    const float c6=c3*c3-s3*s3, s6=2.f*c3*s3;
    const float c7=c6*c1-s6*s1, s7=s6*c1+c6*s1;
    const float cq[8] = {1.f,c1,c2,c3,c4,c5,c6,c7};
    const float sq[8] = {0.f,s1,s2,s3,s4,s5,s6,s7};
#pragma unroll
    for (int q = 1; q < 8; ++q) {
      const f2v r0 = zr[q]*cq[q] - zi[q]*sq[q];
      zi[q] = zr[q]*sq[q] + zi[q]*cq[q];
      zr[q] = r0;
    }
  }
  // transpose 2: unit qb + sA*8 + dd
#pragma unroll
  for (int sA = 0; sA < 8; ++sA) {
    const int fo = FL8(qb + sA*8 + dd) * 4;
    *reinterpret_cast<f2v*>(&buff[fo])     = zr[sA];
    *reinterpret_cast<f2v*>(&buff[fo + 2]) = zi[sA];
  }
#pragma unroll
  for (int d = 0; d < 8; ++d) {
    const float4 q4 = *reinterpret_cast<const float4*>(&buff[FL8(qb + dd*8 + d) * 4]);
    zr[d] = f2v{q4.x, q4.y};
    zi[d] = f2v{q4.z, q4.w};
  }
  dft8p(zr, zi);
  // register r holds Z[k] (both rows), k = 64r + 8*dd + qq

  // ---- untangle to rfft psd: write Z, read conjugate partner ----
#pragma unroll
  for (int r = 0; r < 8; ++r) {
    const int fo = FL8(t*8 + r) * 4;
    *reinterpret_cast<f2v*>(&buff[fo])     = zr[r];
    *reinterpret_cast<f2v*>(&buff[fo + 2]) = zi[r];
  }
  const int pl = (t == 0) ? 0 : ((t < 8) ? (8 - t) : (71 - t));
  const bool lane0 = (t == 0);
  const float kb = (float)((dd << 3) + qq);
  const float ab = -0.0061359231515425649f * kb;          // -pi/512 * (8s+q)
  const float wbr = __cosf(ab), wbi = __sinf(ab);
  constexpr float RCr[8] = {1.f, 0.98078528040323044f, 0.92387953251128674f, 0.83146961230254524f,
                            0.70710678118654752f, 0.55557023301960222f, 0.38268343236508977f, 0.19509032201612827f};
  constexpr float RCi[8] = {0.f, -0.19509032201612827f, -0.38268343236508977f, -0.55557023301960222f,
                            -0.70710678118654752f, -0.83146961230254524f, -0.92387953251128674f, -0.98078528040323044f};
  float psA = 0.f, psB = 0.f, pmA = 0.f, pmB = 0.f, plA = 0.f, plB = 0.f;
#pragma unroll
  for (int r = 0; r < 8; ++r) {
    const int rho = lane0 ? ((8 - r) & 7) : (7 - r);
    const float4 q4 = *reinterpret_cast<const float4*>(&buff[FL8(pl*8 + rho) * 4]);
    const f2v zpr = f2v{q4.x, q4.y};
    const f2v zpi = f2v{q4.z, q4.w};
    const f2v Er = 0.5f*(zr[r] + zpr);
    const f2v Ei = 0.5f*(zi[r] - zpi);
    const f2v Or = 0.5f*(zi[r] + zpi);
    const f2v Oi = -0.5f*(zr[r] - zpr);
    const float wr = wbr*RCr[r] - wbi*RCi[r];
    const float wi = wbr*RCi[r] + wbi*RCr[r];
    const f2v Xr = Er + wr*Or - wi*Oi;
    const f2v Xi = Ei + wr*Oi + wi*Or;
    const f2v pp = Xr*Xr + Xi*Xi;
    const float pa = fmaxf(pp.x, EPSF);
    const float pb = fmaxf(pp.y, EPSF);
    psA += pa; psB += pb;
    pmA = fmaxf(pmA, pa); pmB = fmaxf(pmB, pb);
    plA += pa * __logf(pa);
    plB += pb * __logf(pb);
  }
  float PSUM2[2], PMAX2[2], PLOG2[2];
  PSUM2[0] = rl(wave_red_add(psA), 63);
  PSUM2[1] = rl(wave_red_add(psB), 63);
  PMAX2[0] = rl(wave_red_max_pos(pmA), 63);
  PMAX2[1] = rl(wave_red_max_pos(pmB), 63);
  PLOG2[0] = rl(wave_red_add(plA), 63);
  PLOG2[1] = rl(wave_red_add(plB), 63);

  // ======== per-row tail: features, LN, MLP, stores ========
#pragma unroll 1
  for (int rr = 0; rr < 2; ++rr) {
    const float* st = stats2[wv][rr];
    const int row = rowbase + rr;
    const float PSUM = PSUM2[rr], PMAX = PMAX2[rr], PLOG = PLOG2[rr];

    const float SUMSQ = st[0];
    const float ALT   = st[1];
    const float STR   = st[12];
    const float STR2  = st[13];
    const float SC    = st[14];
    const float SC2   = st[15];
    const float SUMX  = st[16];
    const float x0    = st[37];
    const float xl    = st[38];

    const float p512b = fmaxf(ALT * ALT, EPSF);
    const float Sr    = PSUM + p512b;
    const float invS  = 1.f / Sr;
    const float PLr   = PLOG + p512b * __logf(p512b);
    const float ent   = __logf(Sr) - PLr * invS;
    const float PMX   = fmaxf(PMAX, p512b);

    const float m = SUMX * (1.f / 1024.f);
    const float den = SUMSQ - 1024.f * m * m + EPSF;
    const float invden = 1.f / den;
    float acf1 = 0.f, acf2 = 0.f, lbq = 0.f, R1v = 0.f;
#pragma unroll
    for (int k = 1; k <= 10; ++k) {
      const float Rkv = st[1 + k];
      const float Slo = st[16 + k];
      const float Shi = st[37 - k];
      const float num = Rkv - m * (Shi + (SUMX - Slo)) + (float)(1024 - k) * m * m;
      const float a = fminf(fmaxf(num * invden, -1.f), 1.f);
      if (k == 1) { acf1 = a; R1v = Rkv; }
      else if (k == 2) acf2 = a;
      lbq += a * a;
    }
    const float spent = fminf(fmaxf(ent / (__logf(513.f + EPSF) + EPSF), 0.f), 1.f);
    const float peak  = fminf(fmaxf(PMX / (Sr + EPSF), 0.f), 1.f);
    const float phi = fminf(fmaxf(R1v / ((SUMSQ - xl * xl) + EPSF), -1.f), 1.f);
    const float invn = 1.f / 1023.f;
    const float sum_d2 = 2.f * SUMSQ - x0 * x0 - xl * xl - 2.f * R1v;
    const float md = (xl - x0) * invn;
    const float diff_var = sum_d2 * invn - md * md;
    const float tstr = STR2 * (1.f / 1024.f) - (STR * (1.f / 1024.f)) * (STR * (1.f / 1024.f));
    const float varx = SUMSQ * (1.f / 1024.f) - m * m;
    const float mc = SC * (1.f / 1024.f);
    const float kpss = (SC2 * (1.f / 1024.f) - mc * mc) / (varx + 1e-8f);

    float f[9] = {acf1, acf2, spent, phi, diff_var, tstr, kpss, lbq, peak};
    float fm = 0.f;
#pragma unroll
    for (int d = 0; d < 9; ++d) fm += f[d];
    fm *= (1.f / 9.f);
    float fv = 0.f;
#pragma unroll
    for (int d = 0; d < 9; ++d) { const float tt = f[d] - fm; fv = fmaf(tt, tt, fv); }
    fv *= (1.f / 9.f);
    const float inl = 1.f / sqrtf(fv + 1e-5f);
    float fn[9];
#pragma unroll
    for (int d = 0; d < 9; ++d) fn[d] = (f[d] - fm) * inl * ln_w[d] + ln_b[d];

    float h = b1[t];
#pragma unroll
    for (int d = 0; d < 9; ++d) h = fmaf(fn[d], w1[d * 64 + t], h);
    h = fmaxf(h, 0.f);
    float l0 = h * w2[t * 3 + 0];
    float l1 = h * w2[t * 3 + 1];
    float l2 = h * w2[t * 3 + 2];
    l0 = wave_red_add(l0);
    l1 = wave_red_add(l1);
    l2 = wave_red_add(l2);
    const float L0 = rl(l0, 63) + b2[0];
    const float L1 = rl(l1, 63) + b2[1];
    const float L2 = rl(l2, 63) + b2[2];
    if (t == 0) {
      const float mx = fmaxf(L0, fmaxf(L1, L2));
      const float e0 = __expf(L0 - mx), e1 = __expf(L1 - mx), e2 = __expf(L2 - mx);
      const float is = 1.f / (e0 + e1 + e2);
      float* o = out + (size_t)row * 3;
      o[0] = e0 * is; o[1] = e1 * is; o[2] = e2 * is;
      float* fo = out + (size_t)B * 3 + (size_t)row * 9;
      fo[0] = fn[0]; fo[1] = fn[1]; fo[2] = fn[2]; fo[3] = fn[3]; fo[4] = fn[4];
      fo[5] = fn[5]; fo[6] = fn[6]; fo[7] = fn[7]; fo[8] = fn[8];
    }
  }
}

extern "C" void kernel_launch(void* const* d_in, const int* in_sizes, int n_in,
                              void* d_out, int out_size, void* d_ws, size_t ws_size,
                              hipStream_t stream) {
  (void)n_in; (void)out_size; (void)d_ws; (void)ws_size;
  const float* x    = (const float*)d_in[0];
  const float* ln_w = (const float*)d_in[1];
  const float* ln_b = (const float*)d_in[2];
  const float* w1   = (const float*)d_in[3];
  const float* b1   = (const float*)d_in[4];
  const float* w2   = (const float*)d_in[5];
  const float* b2   = (const float*)d_in[6];
  float* out = (float*)d_out;
  const int B = in_sizes[0] / 1024;
  sr_kernel<<<(B + 3) / 4, 128, 0, stream>>>(x, ln_w, ln_b, w1, b1, w2, b2, out, B);
}